// Round 1
// baseline (1033.897 us; speedup 1.0000x reference)
//
#include <hip/hip_runtime.h>
#include <math.h>

// Problem constants
#define BATCH 8
#define DIMD  512
#define NTOK  1024      // H*W = 32*32
#define NH    8
#define KD    64
#define VD    64
#define CQKV  640       // 64 K + 64 V + 512 Q (8 heads * 64)
#define DOUT  512

// ---------------------------------------------------------------------------
// Kernel 0: repack weights into Wcat[512][640] (row-major, d outer) so the
// QKV GEMM reads B-tiles coalesced.
//   c in [0,64)    -> key_proj[d][c]
//   c in [64,128)  -> value_proj[d][c-64]
//   c in [128,640) -> query_proj[h][k][d] with h*64+k = c-128 (stride-512 read,
//                     done once, cached)
// ---------------------------------------------------------------------------
__global__ void repack_w(const float* __restrict__ qp, const float* __restrict__ kp,
                         const float* __restrict__ vp, float* __restrict__ wcat) {
    int idx = blockIdx.x * blockDim.x + threadIdx.x;
    if (idx >= DIMD * CQKV) return;
    int d = idx / CQKV, c = idx % CQKV;
    float v;
    if (c < 64)       v = kp[d * 64 + c];
    else if (c < 128) v = vp[d * 64 + (c - 64)];
    else              v = qp[(size_t)(c - 128) * DIMD + d];
    wcat[idx] = v;
}

// ---------------------------------------------------------------------------
// Kernel 1: QKV[b][n][c] = sum_d x[b][d][n] * Wcat[d][c]
// Tile: 64 tokens x 64 cols, K-chunk 32.  256 thr, 4x4 micro-tile/thread.
// ---------------------------------------------------------------------------
__global__ __launch_bounds__(256) void qkv_gemm(const float* __restrict__ x,
                                                const float* __restrict__ wcat,
                                                float* __restrict__ qkv) {
    __shared__ float Xs[32][64];   // [d][n]  (stride 64: broadcast reads, 2-way stores -> free)
    __shared__ float Ws[32][64];   // [d][c]
    const int b  = blockIdx.z;
    const int n0 = blockIdx.y * 64;
    const int c0 = blockIdx.x * 64;
    const int t  = threadIdx.x;
    const int ty = t >> 4, tx = t & 15;        // rows ty*4.. , cols tx*4..
    const float* xb = x + (size_t)b * DIMD * NTOK;
    float acc[4][4] = {};

    for (int d0 = 0; d0 < DIMD; d0 += 32) {
        #pragma unroll
        for (int i = 0; i < 8; ++i) {
            int idx = t + i * 256;
            int dd = idx >> 6, nn = idx & 63;
            Xs[dd][nn] = xb[(size_t)(d0 + dd) * NTOK + n0 + nn];
        }
        #pragma unroll
        for (int i = 0; i < 8; ++i) {
            int idx = t + i * 256;
            int dd = idx >> 6, cc = idx & 63;
            Ws[dd][cc] = wcat[(size_t)(d0 + dd) * CQKV + c0 + cc];
        }
        __syncthreads();
        #pragma unroll
        for (int dd = 0; dd < 32; ++dd) {
            float a[4], w[4];
            #pragma unroll
            for (int i = 0; i < 4; ++i) a[i] = Xs[dd][ty * 4 + i];
            #pragma unroll
            for (int j = 0; j < 4; ++j) w[j] = Ws[dd][tx * 4 + j];
            #pragma unroll
            for (int i = 0; i < 4; ++i)
                #pragma unroll
                for (int j = 0; j < 4; ++j) acc[i][j] += a[i] * w[j];
        }
        __syncthreads();
    }
    #pragma unroll
    for (int i = 0; i < 4; ++i)
        #pragma unroll
        for (int j = 0; j < 4; ++j)
            qkv[((size_t)b * NTOK + n0 + ty * 4 + i) * CQKV + c0 + tx * 4 + j] = acc[i][j];
}

// ---------------------------------------------------------------------------
// Kernel 2: attention per (b, h, 64-row Q tile), online softmax over 16
// K/V tiles of 64 rows.  K-tile LDS buffer is reused for P (LDS = ~50 KB).
// Padded stride 65 so stride-64 row reads don't all hit one bank.
// ---------------------------------------------------------------------------
__global__ __launch_bounds__(256) void attn(const float* __restrict__ qkv,
                                            float* __restrict__ o) {
    __shared__ float Qs [64][65];
    __shared__ float KPs[64][65];   // K tile, then reused as P tile
    __shared__ float Vs [64][65];
    const int b  = blockIdx.z;
    const int h  = blockIdx.y;
    const int n0 = blockIdx.x * 64;
    const int t  = threadIdx.x;
    const int ty = t >> 4, tx = t & 15;
    const float* base = qkv + (size_t)b * NTOK * CQKV;
    const float scale = 0.125f;   // 64^-0.5

    #pragma unroll
    for (int i = 0; i < 16; ++i) {
        int idx = t + i * 256;
        int r = idx >> 6, k = idx & 63;
        Qs[r][k] = base[(size_t)(n0 + r) * CQKV + 128 + h * 64 + k];
    }

    float m[4], l[4], oacc[4][4];
    #pragma unroll
    for (int i = 0; i < 4; ++i) {
        m[i] = -1e30f; l[i] = 0.f;
        #pragma unroll
        for (int j = 0; j < 4; ++j) oacc[i][j] = 0.f;
    }

    for (int m0 = 0; m0 < NTOK; m0 += 64) {
        __syncthreads();   // prev P reads done (and Q visible on iter 0 after next sync)
        #pragma unroll
        for (int i = 0; i < 16; ++i) {
            int idx = t + i * 256;
            int r = idx >> 6, k = idx & 63;
            KPs[r][k] = base[(size_t)(m0 + r) * CQKV + k];        // K
            Vs [r][k] = base[(size_t)(m0 + r) * CQKV + 64 + k];   // V
        }
        __syncthreads();

        // S = Q K^T (4x4 per thread)
        float s[4][4] = {};
        #pragma unroll
        for (int kk = 0; kk < 64; ++kk) {
            float a[4], bb[4];
            #pragma unroll
            for (int i = 0; i < 4; ++i) a[i] = Qs[ty * 4 + i][kk];
            #pragma unroll
            for (int j = 0; j < 4; ++j) bb[j] = KPs[tx * 4 + j][kk];
            #pragma unroll
            for (int i = 0; i < 4; ++i)
                #pragma unroll
                for (int j = 0; j < 4; ++j) s[i][j] += a[i] * bb[j];
        }

        // online softmax update (rows spread over the 16 tx lanes of each ty)
        #pragma unroll
        for (int i = 0; i < 4; ++i) {
            #pragma unroll
            for (int j = 0; j < 4; ++j) s[i][j] *= scale;
            float v = fmaxf(fmaxf(s[i][0], s[i][1]), fmaxf(s[i][2], s[i][3]));
            #pragma unroll
            for (int off = 1; off < 16; off <<= 1) v = fmaxf(v, __shfl_xor(v, off, 16));
            float nm    = fmaxf(m[i], v);
            float alpha = __expf(m[i] - nm);
            float ps = 0.f;
            #pragma unroll
            for (int j = 0; j < 4; ++j) { s[i][j] = __expf(s[i][j] - nm); ps += s[i][j]; }
            #pragma unroll
            for (int off = 1; off < 16; off <<= 1) ps += __shfl_xor(ps, off, 16);
            l[i] = l[i] * alpha + ps;
            m[i] = nm;
            #pragma unroll
            for (int j = 0; j < 4; ++j) oacc[i][j] *= alpha;
        }

        __syncthreads();   // all K reads done -> safe to overwrite with P
        #pragma unroll
        for (int i = 0; i < 4; ++i)
            #pragma unroll
            for (int j = 0; j < 4; ++j) KPs[ty * 4 + i][tx * 4 + j] = s[i][j];
        __syncthreads();

        // O += P V
        #pragma unroll
        for (int mm = 0; mm < 64; ++mm) {
            float a[4], bb[4];
            #pragma unroll
            for (int i = 0; i < 4; ++i) a[i] = KPs[ty * 4 + i][mm];
            #pragma unroll
            for (int j = 0; j < 4; ++j) bb[j] = Vs[mm][tx * 4 + j];
            #pragma unroll
            for (int i = 0; i < 4; ++i)
                #pragma unroll
                for (int j = 0; j < 4; ++j) oacc[i][j] += a[i] * bb[j];
        }
    }

    #pragma unroll
    for (int i = 0; i < 4; ++i) {
        float inv = 1.f / l[i];
        #pragma unroll
        for (int j = 0; j < 4; ++j)
            o[((size_t)b * NTOK + n0 + ty * 4 + i) * DOUT + h * 64 + tx * 4 + j] =
                oacc[i][j] * inv;
    }
}

// ---------------------------------------------------------------------------
// Kernel 3: out[b][d][n] = sum_c out_proj[d][c] * O[b][n][c]   (c = h*64+v)
// out_proj is [512][8][64] row-major == [512][512].  Transposed LDS staging.
// ---------------------------------------------------------------------------
__global__ __launch_bounds__(256) void out_gemm(const float* __restrict__ o,
                                                const float* __restrict__ wout,
                                                float* __restrict__ out) {
    __shared__ float Ws2[32][65];  // [c][d]
    __shared__ float Os [32][65];  // [c][n]
    const int b  = blockIdx.z;
    const int d0 = blockIdx.y * 64;
    const int n0 = blockIdx.x * 64;
    const int t  = threadIdx.x;
    const int ty = t >> 4, tx = t & 15;
    const float* ob = o + (size_t)b * NTOK * DOUT;
    float acc[4][4] = {};

    for (int c0 = 0; c0 < DOUT; c0 += 32) {
        #pragma unroll
        for (int i = 0; i < 8; ++i) {
            int idx = t + i * 256;
            int dd = idx >> 5, cc = idx & 31;
            Ws2[cc][dd] = wout[(size_t)(d0 + dd) * DOUT + c0 + cc];
        }
        #pragma unroll
        for (int i = 0; i < 8; ++i) {
            int idx = t + i * 256;
            int nn = idx >> 5, cc = idx & 31;
            Os[cc][nn] = ob[(size_t)(n0 + nn) * DOUT + c0 + cc];
        }
        __syncthreads();
        #pragma unroll
        for (int c = 0; c < 32; ++c) {
            float a[4], bb[4];
            #pragma unroll
            for (int i = 0; i < 4; ++i) a[i] = Ws2[c][ty * 4 + i];
            #pragma unroll
            for (int j = 0; j < 4; ++j) bb[j] = Os[c][tx * 4 + j];
            #pragma unroll
            for (int i = 0; i < 4; ++i)
                #pragma unroll
                for (int j = 0; j < 4; ++j) acc[i][j] += a[i] * bb[j];
        }
        __syncthreads();
    }
    #pragma unroll
    for (int i = 0; i < 4; ++i)
        #pragma unroll
        for (int j = 0; j < 4; ++j)
            out[((size_t)b * DOUT + d0 + ty * 4 + i) * NTOK + n0 + tx * 4 + j] = acc[i][j];
}

// ---------------------------------------------------------------------------
extern "C" void kernel_launch(void* const* d_in, const int* in_sizes, int n_in,
                              void* d_out, int out_size, void* d_ws, size_t ws_size,
                              hipStream_t stream) {
    const float* x  = (const float*)d_in[0];  // [8][512][1024]
    const float* qp = (const float*)d_in[1];  // [8][64][512]
    const float* kp = (const float*)d_in[2];  // [512][64]
    const float* vp = (const float*)d_in[3];  // [512][64]
    const float* op = (const float*)d_in[4];  // [512][8][64] == [512][512]
    float* out = (float*)d_out;               // [8][512][1024]

    float* ws   = (float*)d_ws;
    float* wcat = ws;                                    // 512*640          = 327,680 f
    float* qkv  = wcat + (size_t)DIMD * CQKV;            // 8*1024*640       = 5,242,880 f
    float* obuf = qkv + (size_t)BATCH * NTOK * CQKV;     // 8*1024*512       = 4,194,304 f
    // total ws use: ~39.1 MB

    repack_w<<<(DIMD * CQKV + 255) / 256, 256, 0, stream>>>(qp, kp, vp, wcat);
    qkv_gemm<<<dim3(CQKV / 64, NTOK / 64, BATCH), 256, 0, stream>>>(x, wcat, qkv);
    attn<<<dim3(NTOK / 64, NH, BATCH), 256, 0, stream>>>(qkv, obuf);
    out_gemm<<<dim3(NTOK / 64, DOUT / 64, BATCH), 256, 0, stream>>>(obuf, op, out);
}

// Round 2
// 321.929 us; speedup vs baseline: 3.2116x; 3.2116x over previous
//
#include <hip/hip_runtime.h>
#include <math.h>

// Problem constants
#define BATCH 8
#define DIMD  512
#define NTOK  1024      // H*W = 32*32
#define NH    8
#define KD    64
#define VD    64
#define CQKV  640       // 64 K + 64 V + 512 Q (8 heads * 64)
#define DOUT  512

typedef __attribute__((ext_vector_type(8))) short short8;   // 8 bf16 (4 VGPRs) MFMA A/B frag
typedef __attribute__((ext_vector_type(4))) short short4v;
typedef __attribute__((ext_vector_type(4))) float f32x4;    // MFMA C/D frag

__device__ __forceinline__ short bf16rn(float x) {
    unsigned u = __float_as_uint(x);
    u += 0x7FFF + ((u >> 16) & 1);          // round-to-nearest-even
    return (short)(u >> 16);
}
__device__ __forceinline__ float bf16tof(short s) {
    return __uint_as_float(((unsigned)(unsigned short)s) << 16);
}

// ---------------------------------------------------------------------------
// Kernel 0: repack weights into Wcat[512][640]
// ---------------------------------------------------------------------------
__global__ void repack_w(const float* __restrict__ qp, const float* __restrict__ kp,
                         const float* __restrict__ vp, float* __restrict__ wcat) {
    int idx = blockIdx.x * blockDim.x + threadIdx.x;
    if (idx >= DIMD * CQKV) return;
    int d = idx / CQKV, c = idx % CQKV;
    float v;
    if (c < 64)       v = kp[d * 64 + c];
    else if (c < 128) v = vp[d * 64 + (c - 64)];
    else              v = qp[(size_t)(c - 128) * DIMD + d];
    wcat[idx] = v;
}

// ---------------------------------------------------------------------------
// Kernel 1: QKV[b][n][c] = sum_d x[b][d][n] * Wcat[d][c]   (fp32, unchanged)
// ---------------------------------------------------------------------------
__global__ __launch_bounds__(256) void qkv_gemm(const float* __restrict__ x,
                                                const float* __restrict__ wcat,
                                                float* __restrict__ qkv) {
    __shared__ float Xs[32][64];
    __shared__ float Ws[32][64];
    const int b  = blockIdx.z;
    const int n0 = blockIdx.y * 64;
    const int c0 = blockIdx.x * 64;
    const int t  = threadIdx.x;
    const int ty = t >> 4, tx = t & 15;
    const float* xb = x + (size_t)b * DIMD * NTOK;
    float acc[4][4] = {};

    for (int d0 = 0; d0 < DIMD; d0 += 32) {
        #pragma unroll
        for (int i = 0; i < 8; ++i) {
            int idx = t + i * 256;
            int dd = idx >> 6, nn = idx & 63;
            Xs[dd][nn] = xb[(size_t)(d0 + dd) * NTOK + n0 + nn];
        }
        #pragma unroll
        for (int i = 0; i < 8; ++i) {
            int idx = t + i * 256;
            int dd = idx >> 6, cc = idx & 63;
            Ws[dd][cc] = wcat[(size_t)(d0 + dd) * CQKV + c0 + cc];
        }
        __syncthreads();
        #pragma unroll
        for (int dd = 0; dd < 32; ++dd) {
            float a[4], w[4];
            #pragma unroll
            for (int i = 0; i < 4; ++i) a[i] = Xs[dd][ty * 4 + i];
            #pragma unroll
            for (int j = 0; j < 4; ++j) w[j] = Ws[dd][tx * 4 + j];
            #pragma unroll
            for (int i = 0; i < 4; ++i)
                #pragma unroll
                for (int j = 0; j < 4; ++j) acc[i][j] += a[i] * w[j];
        }
        __syncthreads();
    }
    #pragma unroll
    for (int i = 0; i < 4; ++i)
        #pragma unroll
        for (int j = 0; j < 4; ++j)
            qkv[((size_t)b * NTOK + n0 + ty * 4 + i) * CQKV + c0 + tx * 4 + j] = acc[i][j];
}

// ---------------------------------------------------------------------------
// Kernel 2: MFMA flash attention.
// Block = 256 thr = 4 waves; 128 Q rows per block (32 per wave = 2 row-tiles).
// K/V staged per 64-token tile into LDS in MFMA B-fragment order so frag
// reads are lane-contiguous ds_read_b128 (conflict-free).
// QK^T in split-bf16 (hi/lo, 3 MFMAs) for ~fp32 logit precision; PV in bf16.
// P round-trips through per-wave LDS (col-major, stride 36 shorts) to convert
// C/D layout -> A layout.
// ---------------------------------------------------------------------------
__global__ __launch_bounds__(256) void attn_mfma(const float* __restrict__ qkv,
                                                 float* __restrict__ o) {
    // fragment-order K/V: [mtile(4)][chunk(2)][lane(64)][j(8)] bf16
    __shared__ short Khi[4096];
    __shared__ short Klo[4096];
    __shared__ short Vf [4096];
    // per-wave P, col-major: [m(64)][row(32) stride 36]
    __shared__ short Pbuf[4 * 64 * 36];

    const int b   = blockIdx.z;
    const int h   = blockIdx.y;
    const int n0  = blockIdx.x * 128;
    const int tid = threadIdx.x;
    const int w    = tid >> 6;
    const int lane = tid & 63;
    const int q    = lane >> 4;     // quad
    const int r    = lane & 15;
    const float* base = qkv + (size_t)b * NTOK * CQKV;
    short* Pw = Pbuf + w * (64 * 36);

    // ---- Q fragments (A-operand layout), split hi/lo, held in registers ----
    short8 qhi[2][2], qlo[2][2];    // [row-tile][k-chunk]
    #pragma unroll
    for (int rt = 0; rt < 2; ++rt) {
        #pragma unroll
        for (int c = 0; c < 2; ++c) {
            const float* qp = base + (size_t)(n0 + w * 32 + rt * 16 + r) * CQKV
                              + 128 + h * 64 + c * 32 + q * 8;
            float4 a0 = *(const float4*)qp;
            float4 a1 = *(const float4*)(qp + 4);
            float vals[8] = {a0.x, a0.y, a0.z, a0.w, a1.x, a1.y, a1.z, a1.w};
            #pragma unroll
            for (int j = 0; j < 8; ++j) {
                short hs = bf16rn(vals[j]);
                qhi[rt][c][j] = hs;
                qlo[rt][c][j] = bf16rn(vals[j] - bf16tof(hs));
            }
        }
    }

    f32x4 oacc[2][4];
    float m_[2][4], l_[2][4];
    #pragma unroll
    for (int rt = 0; rt < 2; ++rt) {
        #pragma unroll
        for (int tt = 0; tt < 4; ++tt) oacc[rt][tt] = (f32x4){0.f, 0.f, 0.f, 0.f};
        #pragma unroll
        for (int i = 0; i < 4; ++i) { m_[rt][i] = -1e30f; l_[rt][i] = 0.f; }
    }

    for (int m0 = 0; m0 < NTOK; m0 += 64) {
        __syncthreads();   // all frag reads of previous tile done

        // ---- stage K tile (hi/lo bf16, fragment order) ----
        #pragma unroll
        for (int i = 0; i < 4; ++i) {
            const int mm = i * 16 + (tid >> 4);     // row of K tile
            const int kb = (tid & 15) * 4;          // kd base
            float4 kv = *(const float4*)(base + (size_t)(m0 + mm) * CQKV + kb);
            float kvv[4] = {kv.x, kv.y, kv.z, kv.w};
            short4v h4, l4;
            #pragma unroll
            for (int e = 0; e < 4; ++e) {
                short hs = bf16rn(kvv[e]);
                h4[e] = hs;
                l4[e] = bf16rn(kvv[e] - bf16tof(hs));
            }
            const int c  = kb >> 5, qk = (kb >> 3) & 3, jb = kb & 7;
            const int off = (((i * 2 + c) * 64) + qk * 16 + (tid >> 4)) * 8 + jb;
            *(short4v*)&Khi[off] = h4;
            *(short4v*)&Klo[off] = l4;
        }
        // ---- stage V tile (bf16, fragment order: element V[m][v]) ----
        #pragma unroll
        for (int i = 0; i < 4; ++i) {
            const int mb = w * 4 + i * 16;          // 4-aligned m base
            short4v v4;
            #pragma unroll
            for (int e = 0; e < 4; ++e)
                v4[e] = bf16rn(base[(size_t)(m0 + mb + e) * CQKV + 64 + lane]);
            const int cc = mb >> 5, qv = (mb >> 3) & 3, jb = mb & 7;
            const int tv = lane >> 4, rv = lane & 15;
            const int off = (((tv * 2 + cc) * 64) + qv * 16 + rv) * 8 + jb;
            *(short4v*)&Vf[off] = v4;
        }
        __syncthreads();

        // ---- S = Q K^T (split bf16: hi*hi + hi*lo + lo*hi) ----
        f32x4 s[2][4];
        #pragma unroll
        for (int rt = 0; rt < 2; ++rt)
            #pragma unroll
            for (int tt = 0; tt < 4; ++tt) s[rt][tt] = (f32x4){0.f, 0.f, 0.f, 0.f};

        #pragma unroll
        for (int c = 0; c < 2; ++c) {
            #pragma unroll
            for (int tt = 0; tt < 4; ++tt) {
                short8 kh = *(short8*)&Khi[((tt * 2 + c) * 64 + lane) * 8];
                short8 kl = *(short8*)&Klo[((tt * 2 + c) * 64 + lane) * 8];
                #pragma unroll
                for (int rt = 0; rt < 2; ++rt) {
                    s[rt][tt] = __builtin_amdgcn_mfma_f32_16x16x32_bf16(qhi[rt][c], kh, s[rt][tt], 0, 0, 0);
                    s[rt][tt] = __builtin_amdgcn_mfma_f32_16x16x32_bf16(qhi[rt][c], kl, s[rt][tt], 0, 0, 0);
                    s[rt][tt] = __builtin_amdgcn_mfma_f32_16x16x32_bf16(qlo[rt][c], kh, s[rt][tt], 0, 0, 0);
                }
            }
        }

        // ---- online softmax (rows = quad*4+reg; cols spread over 16 lanes) ----
        #pragma unroll
        for (int rt = 0; rt < 2; ++rt) {
            #pragma unroll
            for (int reg = 0; reg < 4; ++reg) {
                float smax = -1e30f;
                #pragma unroll
                for (int tt = 0; tt < 4; ++tt) {
                    s[rt][tt][reg] *= 0.125f;
                    smax = fmaxf(smax, s[rt][tt][reg]);
                }
                #pragma unroll
                for (int off = 1; off < 16; off <<= 1)
                    smax = fmaxf(smax, __shfl_xor(smax, off, 16));
                float nm    = fmaxf(m_[rt][reg], smax);
                float alpha = __expf(m_[rt][reg] - nm);
                float ps = 0.f;
                #pragma unroll
                for (int tt = 0; tt < 4; ++tt) {
                    float e = __expf(s[rt][tt][reg] - nm);
                    s[rt][tt][reg] = e;
                    ps += e;
                }
                #pragma unroll
                for (int off = 1; off < 16; off <<= 1)
                    ps += __shfl_xor(ps, off, 16);
                l_[rt][reg] = l_[rt][reg] * alpha + ps;
                m_[rt][reg] = nm;
                #pragma unroll
                for (int tt = 0; tt < 4; ++tt) oacc[rt][tt][reg] *= alpha;
            }
        }

        // ---- P -> per-wave LDS (col-major) ; C/D rows are contiguous -> b64 ----
        #pragma unroll
        for (int rt = 0; rt < 2; ++rt) {
            #pragma unroll
            for (int tt = 0; tt < 4; ++tt) {
                short4v p4;
                #pragma unroll
                for (int reg = 0; reg < 4; ++reg) p4[reg] = bf16rn(s[rt][tt][reg]);
                *(short4v*)&Pw[(r + 16 * tt) * 36 + rt * 16 + q * 4] = p4;
            }
        }

        // ---- O += P V ----
        #pragma unroll
        for (int c = 0; c < 2; ++c) {
            short8 pf[2];
            #pragma unroll
            for (int rt = 0; rt < 2; ++rt)
                #pragma unroll
                for (int j = 0; j < 8; ++j)
                    pf[rt][j] = Pw[(c * 32 + q * 8 + j) * 36 + rt * 16 + r];
            #pragma unroll
            for (int tt = 0; tt < 4; ++tt) {
                short8 vf = *(short8*)&Vf[((tt * 2 + c) * 64 + lane) * 8];
                #pragma unroll
                for (int rt = 0; rt < 2; ++rt)
                    oacc[rt][tt] = __builtin_amdgcn_mfma_f32_16x16x32_bf16(pf[rt], vf, oacc[rt][tt], 0, 0, 0);
            }
        }
    }

    // ---- epilogue: normalize and store ----
    #pragma unroll
    for (int rt = 0; rt < 2; ++rt) {
        #pragma unroll
        for (int reg = 0; reg < 4; ++reg) {
            float inv = 1.f / l_[rt][reg];
            #pragma unroll
            for (int tt = 0; tt < 4; ++tt)
                o[((size_t)b * NTOK + n0 + w * 32 + rt * 16 + q * 4 + reg) * DOUT
                  + h * 64 + tt * 16 + r] = oacc[rt][tt][reg] * inv;
        }
    }
}

// ---------------------------------------------------------------------------
// Kernel 3: out[b][d][n] = sum_c out_proj[d][c] * O[b][n][c]   (fp32, unchanged)
// ---------------------------------------------------------------------------
__global__ __launch_bounds__(256) void out_gemm(const float* __restrict__ o,
                                                const float* __restrict__ wout,
                                                float* __restrict__ out) {
    __shared__ float Ws2[32][65];
    __shared__ float Os [32][65];
    const int b  = blockIdx.z;
    const int d0 = blockIdx.y * 64;
    const int n0 = blockIdx.x * 64;
    const int t  = threadIdx.x;
    const int ty = t >> 4, tx = t & 15;
    const float* ob = o + (size_t)b * NTOK * DOUT;
    float acc[4][4] = {};

    for (int c0 = 0; c0 < DOUT; c0 += 32) {
        #pragma unroll
        for (int i = 0; i < 8; ++i) {
            int idx = t + i * 256;
            int dd = idx >> 5, cc = idx & 31;
            Ws2[cc][dd] = wout[(size_t)(d0 + dd) * DOUT + c0 + cc];
        }
        #pragma unroll
        for (int i = 0; i < 8; ++i) {
            int idx = t + i * 256;
            int nn = idx >> 5, cc = idx & 31;
            Os[cc][nn] = ob[(size_t)(n0 + nn) * DOUT + c0 + cc];
        }
        __syncthreads();
        #pragma unroll
        for (int c = 0; c < 32; ++c) {
            float a[4], bb[4];
            #pragma unroll
            for (int i = 0; i < 4; ++i) a[i] = Ws2[c][ty * 4 + i];
            #pragma unroll
            for (int j = 0; j < 4; ++j) bb[j] = Os[c][tx * 4 + j];
            #pragma unroll
            for (int i = 0; i < 4; ++i)
                #pragma unroll
                for (int j = 0; j < 4; ++j) acc[i][j] += a[i] * bb[j];
        }
        __syncthreads();
    }
    #pragma unroll
    for (int i = 0; i < 4; ++i)
        #pragma unroll
        for (int j = 0; j < 4; ++j)
            out[((size_t)b * DOUT + d0 + ty * 4 + i) * NTOK + n0 + tx * 4 + j] = acc[i][j];
}

// ---------------------------------------------------------------------------
extern "C" void kernel_launch(void* const* d_in, const int* in_sizes, int n_in,
                              void* d_out, int out_size, void* d_ws, size_t ws_size,
                              hipStream_t stream) {
    const float* x  = (const float*)d_in[0];  // [8][512][1024]
    const float* qp = (const float*)d_in[1];  // [8][64][512]
    const float* kp = (const float*)d_in[2];  // [512][64]
    const float* vp = (const float*)d_in[3];  // [512][64]
    const float* op = (const float*)d_in[4];  // [512][8][64] == [512][512]
    float* out = (float*)d_out;               // [8][512][1024]

    float* ws   = (float*)d_ws;
    float* wcat = ws;                                    // 512*640
    float* qkv  = wcat + (size_t)DIMD * CQKV;            // 8*1024*640
    float* obuf = qkv + (size_t)BATCH * NTOK * CQKV;     // 8*1024*512

    repack_w<<<(DIMD * CQKV + 255) / 256, 256, 0, stream>>>(qp, kp, vp, wcat);
    qkv_gemm<<<dim3(CQKV / 64, NTOK / 64, BATCH), 256, 0, stream>>>(x, wcat, qkv);
    attn_mfma<<<dim3(NTOK / 128, NH, BATCH), 256, 0, stream>>>(qkv, obuf);
    out_gemm<<<dim3(NTOK / 64, DOUT / 64, BATCH), 256, 0, stream>>>(obuf, op, out);
}

// Round 4
// 196.967 us; speedup vs baseline: 5.2491x; 1.6344x over previous
//
#include <hip/hip_runtime.h>
#include <math.h>

// Problem constants
#define BATCH 8
#define DIMD  512
#define NTOK  1024      // H*W
#define NH    8
#define CQKV  640       // 64 K + 64 V + 512 Q
#define DOUT  512

typedef __attribute__((ext_vector_type(8))) short short8;   // MFMA A/B frag (8 bf16)
typedef __attribute__((ext_vector_type(4))) float f32x4;    // MFMA C/D frag

__device__ __forceinline__ short bf16rn(float x) {
    unsigned u = __float_as_uint(x);
    u += 0x7FFF + ((u >> 16) & 1);
    return (short)(u >> 16);
}
__device__ __forceinline__ float bf16tof(short s) {
    return __uint_as_float(((unsigned)(unsigned short)s) << 16);
}
struct HL { short h, l; };
__device__ __forceinline__ HL bf16split(float x) {
    HL r;
    r.h = bf16rn(x);
    r.l = bf16rn(x - bf16tof(r.h));
    return r;
}
// async global->LDS, 16B/lane; LDS dest = wave-uniform base + lane*16
__device__ __forceinline__ void dma16(const short* g, short* l) {
    __builtin_amdgcn_global_load_lds(
        (const __attribute__((address_space(1))) unsigned int*)g,
        (__attribute__((address_space(3))) unsigned int*)l, 16, 0, 0);
}

// Fragment-order conventions (verified in R2 end-to-end):
//  A-frag: lane=(q=lane>>4, r=lane&15), element A[m=r][k=q*8+j] per 32-k chunk
//  B-frag: element B[ncol=r][k=q*8+j]
//  C/D   : D[m=q*4+reg][ncol=r]
// Global frag buffers: [tile16rows][kchunk32][lane64][j8] = 512 shorts/chunk

// ---------------------------------------------------------------------------
// prepack_w: Wcat[d][c] (c: 0-63 K, 64-127 V, 128+ Q) -> B-frag hi/lo
// Whi/Wlo[ct40][kt16][lane][8]; elem = Wcat[d=kt*32+q*8+j][c=ct*16+r]
// ---------------------------------------------------------------------------
__global__ void prepack_w(const float* __restrict__ qp, const float* __restrict__ kp,
                          const float* __restrict__ vp,
                          short* __restrict__ whi, short* __restrict__ wlo) {
    int tid = blockIdx.x * 256 + threadIdx.x;           // 40960
    int lane = tid & 63, kt = (tid >> 6) & 15, ct = tid >> 10;
    int q = lane >> 4, r = lane & 15;
    int c = ct * 16 + r;
    short8 h, l;
    #pragma unroll
    for (int j = 0; j < 8; ++j) {
        int d = kt * 32 + q * 8 + j;
        float v;
        if (c < 64)       v = kp[d * 64 + c];
        else if (c < 128) v = vp[d * 64 + (c - 64)];
        else              v = qp[(size_t)(c - 128) * DIMD + d];
        HL s = bf16split(v);
        h[j] = s.h; l[j] = s.l;
    }
    *(short8*)&whi[(size_t)tid * 8] = h;
    *(short8*)&wlo[(size_t)tid * 8] = l;
}

// ---------------------------------------------------------------------------
// prepack_x: x[b][d][n] -> A-frag hi/lo  Xhi/Xlo[b][mt64][kt16][lane][8]
// elem = x[b][kt*32+q*8+j][mt*16+r]
// ---------------------------------------------------------------------------
__global__ void prepack_x(const float* __restrict__ x,
                          short* __restrict__ xhi, short* __restrict__ xlo) {
    int tid = blockIdx.x * 256 + threadIdx.x;           // 524288
    int lane = tid & 63, kt = (tid >> 6) & 15, mt = (tid >> 10) & 63, b = tid >> 16;
    int q = lane >> 4, r = lane & 15;
    const float* src = x + ((size_t)b * DIMD + kt * 32 + q * 8) * NTOK + mt * 16 + r;
    short8 h, l;
    #pragma unroll
    for (int j = 0; j < 8; ++j) {
        HL s = bf16split(src[(size_t)j * NTOK]);
        h[j] = s.h; l[j] = s.l;
    }
    *(short8*)&xhi[(size_t)tid * 8] = h;
    *(short8*)&xlo[(size_t)tid * 8] = l;
}

// ---------------------------------------------------------------------------
// qkv_gemm: qkv[b][n][c] = sum_d x^T W, split-bf16 MFMA (3 mfma ~ fp32)
// BM=128(n) BN=64(c) BK=64(d); 4 waves; DMA staging.
// ---------------------------------------------------------------------------
__global__ __launch_bounds__(256) void qkv_gemm(const short* __restrict__ xhi,
                                                const short* __restrict__ xlo,
                                                const short* __restrict__ whi,
                                                const short* __restrict__ wlo,
                                                float* __restrict__ qkv) {
    __shared__ short Ah[8192], Al[8192];    // [mtl8][kc2][lane][8]
    __shared__ short Bh[4096], Bl[4096];    // [ctl4][kc2][lane][8]
    const int b = blockIdx.z, bm = blockIdx.y, cb = blockIdx.x;
    const int tid = threadIdx.x, w = tid >> 6, lane = tid & 63;
    const int q = lane >> 4, r = lane & 15;
    f32x4 acc[2][4];
    #pragma unroll
    for (int i = 0; i < 2; ++i)
        #pragma unroll
        for (int j = 0; j < 4; ++j) acc[i][j] = (f32x4){0.f, 0.f, 0.f, 0.f};

    for (int it = 0; it < 8; ++it) {
        __syncthreads();
        for (int u = w; u < 16; u += 4) {
            size_t ga = ((size_t)((b * 64 + bm * 8 + (u >> 1)) * 16 + it * 2 + (u & 1))) * 512 + lane * 8;
            dma16(xhi + ga, &Ah[u * 512]);
            dma16(xlo + ga, &Al[u * 512]);
            if (u < 8) {
                size_t gb = ((size_t)((cb * 4 + (u >> 1)) * 16 + it * 2 + (u & 1))) * 512 + lane * 8;
                dma16(whi + gb, &Bh[u * 512]);
                dma16(wlo + gb, &Bl[u * 512]);
            }
        }
        __syncthreads();
        #pragma unroll
        for (int kc = 0; kc < 2; ++kc) {
            short8 ah[2], al[2];
            #pragma unroll
            for (int rt = 0; rt < 2; ++rt) {
                ah[rt] = *(short8*)&Ah[(((w * 2 + rt) * 2) + kc) * 512 + lane * 8];
                al[rt] = *(short8*)&Al[(((w * 2 + rt) * 2) + kc) * 512 + lane * 8];
            }
            #pragma unroll
            for (int tt = 0; tt < 4; ++tt) {
                short8 bh = *(short8*)&Bh[(tt * 2 + kc) * 512 + lane * 8];
                short8 bl = *(short8*)&Bl[(tt * 2 + kc) * 512 + lane * 8];
                #pragma unroll
                for (int rt = 0; rt < 2; ++rt) {
                    acc[rt][tt] = __builtin_amdgcn_mfma_f32_16x16x32_bf16(ah[rt], bh, acc[rt][tt], 0, 0, 0);
                    acc[rt][tt] = __builtin_amdgcn_mfma_f32_16x16x32_bf16(ah[rt], bl, acc[rt][tt], 0, 0, 0);
                    acc[rt][tt] = __builtin_amdgcn_mfma_f32_16x16x32_bf16(al[rt], bh, acc[rt][tt], 0, 0, 0);
                }
            }
        }
    }
    const int n_base = bm * 128 + w * 32;
    #pragma unroll
    for (int rt = 0; rt < 2; ++rt)
        #pragma unroll
        for (int reg = 0; reg < 4; ++reg)
            #pragma unroll
            for (int tt = 0; tt < 4; ++tt)
                qkv[((size_t)b * NTOK + n_base + rt * 16 + q * 4 + reg) * CQKV
                    + cb * 64 + tt * 16 + r] = acc[rt][tt][reg];
}

// ---------------------------------------------------------------------------
// prepack_kv: qkv fp32 -> K hi/lo + V bf16 in B-frag order per 64-row tile.
// K: [b][t16][ic8=(i*2+c)][lane][8]; elem K[m=t*64+i*16+r][kd=c*32+q*8+j]
// V: [b][t16][tc8=(tv*2+cc)][lane][8]; elem V[m=cc*32+q*8+j][v=tv*16+r]
// ---------------------------------------------------------------------------
__global__ void prepack_kv(const float* __restrict__ qkv, short* __restrict__ khi,
                           short* __restrict__ klo, short* __restrict__ vf) {
    int tid = blockIdx.x * 256 + threadIdx.x;           // 131072
    int lane = tid & 63, q = lane >> 4, r = lane & 15;
    int half = tid >> 16;
    int u = tid & 0xFFFF;
    int ic = (u >> 6) & 7, t = (u >> 9) & 15, b = u >> 13;
    if (half == 0) {
        int i = ic >> 1, c = ic & 1;
        const float* src = qkv + ((size_t)b * NTOK + t * 64 + i * 16 + r) * CQKV + c * 32 + q * 8;
        short8 h, l;
        #pragma unroll
        for (int j = 0; j < 8; ++j) {
            HL s = bf16split(src[j]);
            h[j] = s.h; l[j] = s.l;
        }
        *(short8*)&khi[(size_t)u * 8] = h;
        *(short8*)&klo[(size_t)u * 8] = l;
    } else {
        int tv = ic >> 1, cc = ic & 1;
        const float* src = qkv + ((size_t)b * NTOK + t * 64 + cc * 32 + q * 8) * CQKV + 64 + tv * 16 + r;
        short8 v;
        #pragma unroll
        for (int j = 0; j < 8; ++j) v[j] = bf16rn(src[(size_t)j * CQKV]);
        *(short8*)&vf[(size_t)u * 8] = v;
    }
}

// ---------------------------------------------------------------------------
// prepack_wout: out_proj fp32 -> A-frag bf16  Wof[mt32][kt16][lane][8]
// elem = wout[d=mt*16+r][c=kt*32+q*8+j]
// ---------------------------------------------------------------------------
__global__ void prepack_wout(const float* __restrict__ wout, short* __restrict__ wof) {
    int tid = blockIdx.x * 256 + threadIdx.x;           // 32768
    int lane = tid & 63, kt = (tid >> 6) & 15, mt = tid >> 10;
    int q = lane >> 4, r = lane & 15;
    const float* src = wout + (size_t)(mt * 16 + r) * DOUT + kt * 32 + q * 8;
    short8 h;
    #pragma unroll
    for (int j = 0; j < 8; ++j) h[j] = bf16rn(src[j]);
    *(short8*)&wof[(size_t)tid * 8] = h;
}

// ---------------------------------------------------------------------------
// attn: MFMA flash attention, DMA-staged preconverted K/V.
// Writes O as bf16 B-frags: Ob[b][nt64][ct16][lane][8]; elem O[n=nt*16+r][c=ct*32+q*8+j]
// ---------------------------------------------------------------------------
__global__ __launch_bounds__(256) void attn_mfma(const float* __restrict__ qkv,
                                                 const short* __restrict__ khi_g,
                                                 const short* __restrict__ klo_g,
                                                 const short* __restrict__ vf_g,
                                                 short* __restrict__ ob) {
    __shared__ short Khi[4096], Klo[4096], Vf[4096];
    __shared__ short Pbuf[4 * 64 * 36];
    const int b   = blockIdx.z;
    const int h   = blockIdx.y;
    const int n0  = blockIdx.x * 128;
    const int tid = threadIdx.x;
    const int w    = tid >> 6;
    const int lane = tid & 63;
    const int q    = lane >> 4;
    const int r    = lane & 15;
    const float* base = qkv + (size_t)b * NTOK * CQKV;
    short* Pw = Pbuf + w * (64 * 36);

    // Q fragments, split hi/lo (fp32 source, converted once per block)
    short8 qhi[2][2], qlo[2][2];
    #pragma unroll
    for (int rt = 0; rt < 2; ++rt) {
        #pragma unroll
        for (int c = 0; c < 2; ++c) {
            const float* qp = base + (size_t)(n0 + w * 32 + rt * 16 + r) * CQKV
                              + 128 + h * 64 + c * 32 + q * 8;
            float4 a0 = *(const float4*)qp;
            float4 a1 = *(const float4*)(qp + 4);
            float vals[8] = {a0.x, a0.y, a0.z, a0.w, a1.x, a1.y, a1.z, a1.w};
            #pragma unroll
            for (int j = 0; j < 8; ++j) {
                HL s = bf16split(vals[j]);
                qhi[rt][c][j] = s.h;
                qlo[rt][c][j] = s.l;
            }
        }
    }

    f32x4 oacc[2][4];
    float m_[2][4], l_[2][4];
    #pragma unroll
    for (int rt = 0; rt < 2; ++rt) {
        #pragma unroll
        for (int tt = 0; tt < 4; ++tt) oacc[rt][tt] = (f32x4){0.f, 0.f, 0.f, 0.f};
        #pragma unroll
        for (int i = 0; i < 4; ++i) { m_[rt][i] = -1e30f; l_[rt][i] = 0.f; }
    }

    for (int t = 0; t < 16; ++t) {
        __syncthreads();
        const size_t kb = ((size_t)(b * 16 + t) * 8) * 512;
        for (int ch = w; ch < 8; ch += 4) {
            dma16(khi_g + kb + ch * 512 + lane * 8, &Khi[ch * 512]);
            dma16(klo_g + kb + ch * 512 + lane * 8, &Klo[ch * 512]);
            dma16(vf_g  + kb + ch * 512 + lane * 8, &Vf [ch * 512]);
        }
        __syncthreads();

        // S = Q K^T  (hi*hi + hi*lo + lo*hi)
        f32x4 s[2][4];
        #pragma unroll
        for (int rt = 0; rt < 2; ++rt)
            #pragma unroll
            for (int tt = 0; tt < 4; ++tt) s[rt][tt] = (f32x4){0.f, 0.f, 0.f, 0.f};
        #pragma unroll
        for (int c = 0; c < 2; ++c) {
            #pragma unroll
            for (int tt = 0; tt < 4; ++tt) {
                short8 kh = *(short8*)&Khi[((tt * 2 + c) * 64 + lane) * 8];
                short8 kl = *(short8*)&Klo[((tt * 2 + c) * 64 + lane) * 8];
                #pragma unroll
                for (int rt = 0; rt < 2; ++rt) {
                    s[rt][tt] = __builtin_amdgcn_mfma_f32_16x16x32_bf16(qhi[rt][c], kh, s[rt][tt], 0, 0, 0);
                    s[rt][tt] = __builtin_amdgcn_mfma_f32_16x16x32_bf16(qhi[rt][c], kl, s[rt][tt], 0, 0, 0);
                    s[rt][tt] = __builtin_amdgcn_mfma_f32_16x16x32_bf16(qlo[rt][c], kh, s[rt][tt], 0, 0, 0);
                }
            }
        }

        // online softmax
        #pragma unroll
        for (int rt = 0; rt < 2; ++rt) {
            #pragma unroll
            for (int reg = 0; reg < 4; ++reg) {
                float smax = -1e30f;
                #pragma unroll
                for (int tt = 0; tt < 4; ++tt) {
                    s[rt][tt][reg] *= 0.125f;
                    smax = fmaxf(smax, s[rt][tt][reg]);
                }
                #pragma unroll
                for (int off = 1; off < 16; off <<= 1)
                    smax = fmaxf(smax, __shfl_xor(smax, off, 16));
                float nm    = fmaxf(m_[rt][reg], smax);
                float alpha = __expf(m_[rt][reg] - nm);
                float ps = 0.f;
                #pragma unroll
                for (int tt = 0; tt < 4; ++tt) {
                    float e = __expf(s[rt][tt][reg] - nm);
                    s[rt][tt][reg] = e;
                    ps += e;
                }
                #pragma unroll
                for (int off = 1; off < 16; off <<= 1)
                    ps += __shfl_xor(ps, off, 16);
                l_[rt][reg] = l_[rt][reg] * alpha + ps;
                m_[rt][reg] = nm;
                #pragma unroll
                for (int tt = 0; tt < 4; ++tt) oacc[rt][tt][reg] *= alpha;
            }
        }

        // P -> per-wave LDS (col-major, stride 36)
        #pragma unroll
        for (int rt = 0; rt < 2; ++rt) {
            #pragma unroll
            for (int tt = 0; tt < 4; ++tt) {
                typedef __attribute__((ext_vector_type(4))) short s4;
                s4 p4;
                #pragma unroll
                for (int reg = 0; reg < 4; ++reg) p4[reg] = bf16rn(s[rt][tt][reg]);
                *(s4*)&Pw[(r + 16 * tt) * 36 + rt * 16 + q * 4] = p4;
            }
        }

        // O += P V
        #pragma unroll
        for (int c = 0; c < 2; ++c) {
            short8 pf[2];
            #pragma unroll
            for (int rt = 0; rt < 2; ++rt)
                #pragma unroll
                for (int j = 0; j < 8; ++j)
                    pf[rt][j] = Pw[(c * 32 + q * 8 + j) * 36 + rt * 16 + r];
            #pragma unroll
            for (int tt = 0; tt < 4; ++tt) {
                short8 vfr = *(short8*)&Vf[((tt * 2 + c) * 64 + lane) * 8];
                #pragma unroll
                for (int rt = 0; rt < 2; ++rt)
                    oacc[rt][tt] = __builtin_amdgcn_mfma_f32_16x16x32_bf16(pf[rt], vfr, oacc[rt][tt], 0, 0, 0);
            }
        }
    }

    // epilogue: normalize, write O as bf16 B-frags
    #pragma unroll
    for (int rt = 0; rt < 2; ++rt) {
        const int nt = (n0 + w * 32 + rt * 16) >> 4;
        #pragma unroll
        for (int reg = 0; reg < 4; ++reg) {
            float inv = 1.f / l_[rt][reg];
            #pragma unroll
            for (int tt = 0; tt < 4; ++tt) {
                int ct = h * 2 + (tt >> 1);
                int lanep = ((tt & 1) * 2 + (r >> 3)) * 16 + q * 4 + reg;
                ob[((((size_t)b * 64 + nt) * 16 + ct) * 64 + lanep) * 8 + (r & 7)] =
                    bf16rn(oacc[rt][tt][reg] * inv);
            }
        }
    }
}

// ---------------------------------------------------------------------------
// out_gemm: out[b][d][n] = sum_c wout[d][c] * O[b][n][c], plain bf16 MFMA.
// BM=128(d) BN=64(n) BK=64(c).
// ---------------------------------------------------------------------------
__global__ __launch_bounds__(256) void out_gemm(const short* __restrict__ wof,
                                                const short* __restrict__ obf,
                                                float* __restrict__ out) {
    __shared__ short Ah[8192];   // [mtl8][kc2][lane][8]
    __shared__ short Bh[4096];   // [ntl4][kc2][lane][8]
    const int b = blockIdx.z, bd = blockIdx.y, bn = blockIdx.x;
    const int tid = threadIdx.x, w = tid >> 6, lane = tid & 63;
    const int q = lane >> 4, r = lane & 15;
    f32x4 acc[2][4];
    #pragma unroll
    for (int i = 0; i < 2; ++i)
        #pragma unroll
        for (int j = 0; j < 4; ++j) acc[i][j] = (f32x4){0.f, 0.f, 0.f, 0.f};

    for (int it = 0; it < 8; ++it) {
        __syncthreads();
        for (int u = w; u < 16; u += 4) {
            size_t ga = ((size_t)((bd * 8 + (u >> 1)) * 16 + it * 2 + (u & 1))) * 512 + lane * 8;
            dma16(wof + ga, &Ah[u * 512]);
            if (u < 8) {
                size_t gb = ((size_t)((b * 64 + bn * 4 + (u >> 1)) * 16 + it * 2 + (u & 1))) * 512 + lane * 8;
                dma16(obf + gb, &Bh[u * 512]);
            }
        }
        __syncthreads();
        #pragma unroll
        for (int kc = 0; kc < 2; ++kc) {
            short8 a0 = *(short8*)&Ah[((w * 2 + 0) * 2 + kc) * 512 + lane * 8];
            short8 a1 = *(short8*)&Ah[((w * 2 + 1) * 2 + kc) * 512 + lane * 8];
            #pragma unroll
            for (int tt = 0; tt < 4; ++tt) {
                short8 bb = *(short8*)&Bh[(tt * 2 + kc) * 512 + lane * 8];
                acc[0][tt] = __builtin_amdgcn_mfma_f32_16x16x32_bf16(a0, bb, acc[0][tt], 0, 0, 0);
                acc[1][tt] = __builtin_amdgcn_mfma_f32_16x16x32_bf16(a1, bb, acc[1][tt], 0, 0, 0);
            }
        }
    }
    const int d_base = bd * 128 + w * 32;
    #pragma unroll
    for (int rt = 0; rt < 2; ++rt)
        #pragma unroll
        for (int reg = 0; reg < 4; ++reg)
            #pragma unroll
            for (int tt = 0; tt < 4; ++tt)
                out[((size_t)b * DOUT + d_base + rt * 16 + q * 4 + reg) * NTOK
                    + bn * 64 + tt * 16 + r] = acc[rt][tt][reg];
}

// ---------------------------------------------------------------------------
extern "C" void kernel_launch(void* const* d_in, const int* in_sizes, int n_in,
                              void* d_out, int out_size, void* d_ws, size_t ws_size,
                              hipStream_t stream) {
    const float* x  = (const float*)d_in[0];
    const float* qp = (const float*)d_in[1];
    const float* kp = (const float*)d_in[2];
    const float* vp = (const float*)d_in[3];
    const float* op = (const float*)d_in[4];
    float* out = (float*)d_out;

    // workspace layout (39.06 MB total, with aliasing)
    short* Whi = (short*)d_ws;                 // 327,680 shorts
    short* Wlo = Whi + 327680;                 // 327,680
    short* Xhi = Wlo + 327680;                 // 4,194,304
    short* Xlo = Xhi + 4194304;                // 4,194,304
    float* qkvb = (float*)(Xlo + 4194304);     // 5,242,880 floats
    // aliases (safe by stream ordering):
    short* Ob  = Xhi;                          // written in attn, after Xhi last read
    short* Wof = Xlo;                          // 262,144 shorts
    short* Khi = Xlo + 262144;                 // 524,288
    short* Klo = Khi + 524288;                 // 524,288
    short* Vf  = Klo + 524288;                 // 524,288  (total 1,835,008 <= 4,194,304)

    prepack_w  <<<160,  256, 0, stream>>>(qp, kp, vp, Whi, Wlo);
    prepack_x  <<<2048, 256, 0, stream>>>(x, Xhi, Xlo);
    qkv_gemm   <<<dim3(10, 8, BATCH), 256, 0, stream>>>(Xhi, Xlo, Whi, Wlo, qkvb);
    prepack_kv <<<512,  256, 0, stream>>>(qkvb, Khi, Klo, Vf);
    prepack_wout<<<128, 256, 0, stream>>>(op, Wof);
    attn_mfma  <<<dim3(8, NH, BATCH), 256, 0, stream>>>(qkvb, Khi, Klo, Vf, Ob);
    out_gemm   <<<dim3(16, 4, BATCH), 256, 0, stream>>>(Wof, Ob, out);
}